// Round 22
// baseline (561.297 us; speedup 1.0000x reference)
//
#include <hip/hip_runtime.h>
#include <hip/hip_bf16.h>
#include <cstdint>
#include <cstddef>

// Problem dims
#define HD   768
#define ID   3072
#define NB   4
#define SL   2048
#define NL   4
#define ROWS (NB*SL)   // 8192

typedef __attribute__((ext_vector_type(8))) short bf16x8s;
typedef __attribute__((ext_vector_type(4))) float f32x4;
typedef __attribute__((ext_vector_type(4))) unsigned short u16x4;

typedef __attribute__((address_space(1))) const unsigned int g_as1_u32;
typedef __attribute__((address_space(3))) unsigned int lds_as3_u32;

// async 16B/lane global->LDS copy (wave-uniform LDS base + lane*16)
__device__ __forceinline__ void gl2lds16(__hip_bfloat16* l, const __hip_bfloat16* g) {
  __builtin_amdgcn_global_load_lds((g_as1_u32*)g, (lds_as3_u32*)l, 16, 0, 0);
}

__device__ __forceinline__ float bfu2f(unsigned short u) {
  return __uint_as_float((unsigned int)u << 16);
}
__device__ __forceinline__ unsigned short f2bfu(float f) {
  __hip_bfloat16 h = __float2bfloat16(f);
  return *reinterpret_cast<unsigned short*>(&h);
}

// ---------------------------------------------------------------------------
// Wave-per-row LayerNorm: block=256 (4 waves), wave w does row blockIdx*4+w.
// ---------------------------------------------------------------------------
template <int OUTF32>
__global__ __launch_bounds__(256) void ln_row_kernel(
    const __hip_bfloat16* __restrict__ x,
    const float* __restrict__ scale, const float* __restrict__ bias,
    __hip_bfloat16* __restrict__ ob, float* __restrict__ of)
{
  const int w = threadIdx.x >> 6, lane = threadIdx.x & 63;
  const size_t row = (size_t)blockIdx.x * 4 + w;
  const __hip_bfloat16* xr = x + row * HD;
  float v[12];
#pragma unroll
  for (int c = 0; c < 3; c++) {
    u16x4 u = *reinterpret_cast<const u16x4*>(xr + c * 256 + lane * 4);
#pragma unroll
    for (int i = 0; i < 4; i++) v[c * 4 + i] = bfu2f(u[i]);
  }
  float s = 0.f;
#pragma unroll
  for (int i = 0; i < 12; i++) s += v[i];
#pragma unroll
  for (int m = 1; m < 64; m <<= 1) s += __shfl_xor(s, m);
  float mean = s * (1.0f / 768.0f);
  float q = 0.f;
#pragma unroll
  for (int i = 0; i < 12; i++) { float d = v[i] - mean; q += d * d; }
#pragma unroll
  for (int m = 1; m < 64; m <<= 1) q += __shfl_xor(q, m);
  float rstd = rsqrtf(q * (1.0f / 768.0f) + 1e-5f);
#pragma unroll
  for (int c = 0; c < 3; c++) {
    int j0 = c * 256 + lane * 4;
    if (OUTF32) {
      f32x4 o;
#pragma unroll
      for (int i = 0; i < 4; i++)
        o[i] = (v[c * 4 + i] - mean) * rstd * scale[j0 + i] + bias[j0 + i];
      *reinterpret_cast<f32x4*>(of + row * HD + j0) = o;
    } else {
      u16x4 o;
#pragma unroll
      for (int i = 0; i < 4; i++)
        o[i] = f2bfu((v[c * 4 + i] - mean) * rstd * scale[j0 + i] + bias[j0 + i]);
      *reinterpret_cast<u16x4*>(ob + row * HD + j0) = o;
    }
  }
}

// ---------------------------------------------------------------------------
// Fused LN2 + final LN (last layer only): out = LNf(bf16(LN2(y))).
// ---------------------------------------------------------------------------
__global__ __launch_bounds__(256) void ln2_final_kernel(
    const __hip_bfloat16* __restrict__ y,
    const float* __restrict__ s2, const float* __restrict__ b2,
    const float* __restrict__ fs, const float* __restrict__ fb,
    float* __restrict__ out)
{
  const int w = threadIdx.x >> 6, lane = threadIdx.x & 63;
  const size_t row = (size_t)blockIdx.x * 4 + w;
  const __hip_bfloat16* xr = y + row * HD;
  float v[12];
#pragma unroll
  for (int c = 0; c < 3; c++) {
    u16x4 u = *reinterpret_cast<const u16x4*>(xr + c * 256 + lane * 4);
#pragma unroll
    for (int i = 0; i < 4; i++) v[c * 4 + i] = bfu2f(u[i]);
  }
  float s = 0.f;
#pragma unroll
  for (int i = 0; i < 12; i++) s += v[i];
#pragma unroll
  for (int m = 1; m < 64; m <<= 1) s += __shfl_xor(s, m);
  float mean = s * (1.0f / 768.0f);
  float q = 0.f;
#pragma unroll
  for (int i = 0; i < 12; i++) { float d = v[i] - mean; q += d * d; }
#pragma unroll
  for (int m = 1; m < 64; m <<= 1) q += __shfl_xor(q, m);
  float rstd = rsqrtf(q * (1.0f / 768.0f) + 1e-5f);
  // LN2 result, rounded to bf16 exactly as the unfused path stored it
  float t[12];
#pragma unroll
  for (int c = 0; c < 3; c++) {
    int j0 = c * 256 + lane * 4;
#pragma unroll
    for (int i = 0; i < 4; i++)
      t[c * 4 + i] = bfu2f(f2bfu((v[c * 4 + i] - mean) * rstd * s2[j0 + i] + b2[j0 + i]));
  }
  // final LN over t
  float s2m = 0.f;
#pragma unroll
  for (int i = 0; i < 12; i++) s2m += t[i];
#pragma unroll
  for (int m = 1; m < 64; m <<= 1) s2m += __shfl_xor(s2m, m);
  float mean2 = s2m * (1.0f / 768.0f);
  float q2 = 0.f;
#pragma unroll
  for (int i = 0; i < 12; i++) { float d = t[i] - mean2; q2 += d * d; }
#pragma unroll
  for (int m = 1; m < 64; m <<= 1) q2 += __shfl_xor(q2, m);
  float rstd2 = rsqrtf(q2 * (1.0f / 768.0f) + 1e-5f);
#pragma unroll
  for (int c = 0; c < 3; c++) {
    int j0 = c * 256 + lane * 4;
    f32x4 o;
#pragma unroll
    for (int i = 0; i < 4; i++)
      o[i] = (t[c * 4 + i] - mean2) * rstd2 * fs[j0 + i] + fb[j0 + i];
    *reinterpret_cast<f32x4*>(out + row * HD + j0) = o;
  }
}

// embedding gather + pos add + LN (wave-per-row), writes bf16
__global__ __launch_bounds__(256) void embed_ln_kernel(
    const int* __restrict__ ids, const float* __restrict__ wemb,
    const float* __restrict__ pemb,
    const float* __restrict__ scale, const float* __restrict__ bias,
    __hip_bfloat16* __restrict__ ob)
{
  const int w = threadIdx.x >> 6, lane = threadIdx.x & 63;
  const size_t row = (size_t)blockIdx.x * 4 + w;
  const int t = (int)(row & (SL - 1));
  const int id = ids[row];
  float v[12];
#pragma unroll
  for (int c = 0; c < 3; c++) {
    int j0 = c * 256 + lane * 4;
    f32x4 a = *reinterpret_cast<const f32x4*>(wemb + (size_t)id * HD + j0);
    f32x4 p = *reinterpret_cast<const f32x4*>(pemb + (size_t)t * HD + j0);
#pragma unroll
    for (int i = 0; i < 4; i++) v[c * 4 + i] = a[i] + p[i];
  }
  float s = 0.f;
#pragma unroll
  for (int i = 0; i < 12; i++) s += v[i];
#pragma unroll
  for (int m = 1; m < 64; m <<= 1) s += __shfl_xor(s, m);
  float mean = s * (1.0f / 768.0f);
  float q = 0.f;
#pragma unroll
  for (int i = 0; i < 12; i++) { float d = v[i] - mean; q += d * d; }
#pragma unroll
  for (int m = 1; m < 64; m <<= 1) q += __shfl_xor(q, m);
  float rstd = rsqrtf(q * (1.0f / 768.0f) + 1e-5f);
#pragma unroll
  for (int c = 0; c < 3; c++) {
    int j0 = c * 256 + lane * 4;
    u16x4 o;
#pragma unroll
    for (int i = 0; i < 4; i++)
      o[i] = f2bfu((v[c * 4 + i] - mean) * rstd * scale[j0 + i] + bias[j0 + i]);
    *reinterpret_cast<u16x4*>(ob + row * HD + j0) = o;
  }
}

// ---------------------------------------------------------------------------
// Merged weight transpose + f32->bf16 for retW, W1, W2 (single launch).
// ---------------------------------------------------------------------------
__global__ __launch_bounds__(256) void transpose_all_kernel(
    const float* __restrict__ retW, const float* __restrict__ W1,
    const float* __restrict__ W2,
    __hip_bfloat16* __restrict__ retWt, __hip_bfloat16* __restrict__ W1t,
    __hip_bfloat16* __restrict__ W2t)
{
  __shared__ float tile[32][33];
  int id = blockIdx.x;
  const float* in; __hip_bfloat16* outp; int K, N, n0, k0;
  if (id < 2304) {                          // retW [l][K=HD][N=HD]
    int l = id / 576, rem = id % 576;
    K = HD; N = HD;
    n0 = (rem % 24) * 32; k0 = (rem / 24) * 32;
    in = retW + (size_t)l * HD * HD; outp = retWt + (size_t)l * HD * HD;
  } else if (id < 2304 + 9216) {            // W1 [l][K=HD][N=ID]
    int id2 = id - 2304;
    int l = id2 / 2304, rem = id2 % 2304;
    K = HD; N = ID;
    n0 = (rem % 96) * 32; k0 = (rem / 96) * 32;
    in = W1 + (size_t)l * HD * ID; outp = W1t + (size_t)l * HD * ID;
  } else {                                  // W2 [l][K=ID][N=HD]
    int id2 = id - 2304 - 9216;
    int l = id2 / 2304, rem = id2 % 2304;
    K = ID; N = HD;
    n0 = (rem % 24) * 32; k0 = (rem / 24) * 32;
    in = W2 + (size_t)l * ID * HD; outp = W2t + (size_t)l * ID * HD;
  }
  int tx = threadIdx.x, ty = threadIdx.y;   // (32, 8)
#pragma unroll
  for (int i = 0; i < 4; i++)
    tile[ty + i * 8][tx] = in[(size_t)(k0 + ty + i * 8) * N + n0 + tx];
  __syncthreads();
#pragma unroll
  for (int i = 0; i < 4; i++)
    outp[(size_t)(n0 + ty + i * 8) * K + k0 + tx] = __float2bfloat16(tile[tx][ty + i * 8]);
}

// ---------------------------------------------------------------------------
// Fused retention scan + residual + LN1 (warm-up 16: 0.5^16 ~ 1.5e-5).
// ---------------------------------------------------------------------------
__global__ __launch_bounds__(768) void scan_ln_kernel(
    const __hip_bfloat16* __restrict__ s,
    const __hip_bfloat16* __restrict__ h,
    const float* __restrict__ scale, const float* __restrict__ bias,
    __hip_bfloat16* __restrict__ h1)
{
  __shared__ __hip_bfloat16 zt[32][HD];     // 48 KB
  const int col = threadIdx.x;              // 0..767
  const int nchunk = SL / 32;               // 64
  const int c = blockIdx.x & (nchunk - 1);
  const int b = blockIdx.x / nchunk;
  const int tstart = c * 32;
  int t0 = tstart - 16; if (t0 < 0) t0 = 0;
  const __hip_bfloat16* sp = s + (size_t)b * SL * HD + col;
  const __hip_bfloat16* hp = h + (size_t)b * SL * HD + col;
  float acc = 0.f;
#pragma unroll 8
  for (int t = t0; t < tstart; ++t)
    acc = 0.5f * (__bfloat162float(sp[(size_t)t * HD]) + acc);
#pragma unroll 8
  for (int tt = 0; tt < 32; ++tt) {
    int t = tstart + tt;
    acc = 0.5f * (__bfloat162float(sp[(size_t)t * HD]) + acc);
    zt[tt][col] = __float2bfloat16(acc + __bfloat162float(hp[(size_t)t * HD]));
  }
  __syncthreads();
  // LN phase: 12 waves, wave wv handles rows wv, wv+12, wv+24 (<32)
  const int wv = threadIdx.x >> 6, lane = threadIdx.x & 63;
  for (int row = wv; row < 32; row += 12) {
    float v[12];
#pragma unroll
    for (int cc = 0; cc < 3; cc++) {
      u16x4 u = *reinterpret_cast<const u16x4*>(&zt[row][cc * 256 + lane * 4]);
#pragma unroll
      for (int i = 0; i < 4; i++) v[cc * 4 + i] = bfu2f(u[i]);
    }
    float sm = 0.f;
#pragma unroll
    for (int i = 0; i < 12; i++) sm += v[i];
#pragma unroll
    for (int m = 1; m < 64; m <<= 1) sm += __shfl_xor(sm, m);
    float mean = sm * (1.0f / 768.0f);
    float q = 0.f;
#pragma unroll
    for (int i = 0; i < 12; i++) { float d = v[i] - mean; q += d * d; }
#pragma unroll
    for (int m = 1; m < 64; m <<= 1) q += __shfl_xor(q, m);
    float rstd = rsqrtf(q * (1.0f / 768.0f) + 1e-5f);
    __hip_bfloat16* orow = h1 + ((size_t)b * SL + tstart + row) * HD;
#pragma unroll
    for (int cc = 0; cc < 3; cc++) {
      int j0 = cc * 256 + lane * 4;
      u16x4 o;
#pragma unroll
      for (int i = 0; i < 4; i++)
        o[i] = f2bfu((v[cc * 4 + i] - mean) * rstd * scale[j0 + i] + bias[j0 + i]);
      *reinterpret_cast<u16x4*>(orow + j0) = o;
    }
  }
}

// ---------------------------------------------------------------------------
// Counted-vmcnt pipelined MFMA GEMM (r12 schedule) + coalesced LDS epilogue.
// BM=128, 4 waves (256 thr), BK=64, 2 LDS buffers.
// BN in {96,128,192}; per-wave N sub-tile = BN/2 (NF = BN/32 frags).
// ---------------------------------------------------------------------------
template <int BN, int ACT, int RADD>
__global__ __launch_bounds__(256, 2) void gemm_mfma_kernel(
    const __hip_bfloat16* __restrict__ A,
    const __hip_bfloat16* __restrict__ Bt,
    const float* __restrict__ bias,
    const __hip_bfloat16* __restrict__ R,
    __hip_bfloat16* __restrict__ Cb,
    int M, int N, int K)
{
  constexpr int NF = BN / 32;               // N-frags per wave: 3,4,6
  constexpr int BPASS = BN / 32;            // B staging passes (32 rows each)
  constexpr int ABUF = 128 * 64;            // A buffer elems (16KB)
  constexpr int BBUF = BN * 64;             // B buffer elems (12/16/24KB)
  constexpr int CP = BN + 8;                // padded C-tile stride (elems)
  static_assert(128 * CP <= 2 * ABUF + 2 * BBUF, "C tile must fit in smem");
  __shared__ __align__(16) __hip_bfloat16 smem[2 * ABUF + 2 * BBUF];
  __hip_bfloat16* As = smem;
  __hip_bfloat16* Bs = smem + 2 * ABUF;
  const int m0 = blockIdx.x * 128;
  const int n0 = blockIdx.y * BN;
  const int tid  = threadIdx.x;
  const int lane = tid & 63;
  const int w    = tid >> 6;                // wave 0..3
  const int wr   = w >> 1;                  // 0..1 (M half, 64 rows)
  const int wc   = w & 1;                   // 0..1 (N half)
  const int lr   = lane & 15;
  const int kg   = lane >> 4;               // 0..3

  f32x4 acc[4][NF];
#pragma unroll
  for (int i = 0; i < 4; i++)
#pragma unroll
    for (int j = 0; j < NF; j++) acc[i][j] = (f32x4){0.f, 0.f, 0.f, 0.f};

  // staging: pass = 256 thr x 16B = 32 rows x 128B. Wave w rows w*8..w*8+7.
  // lane l: row w*8 + l/8, LDS slot l%8, global k-slot (l%8)^(l/8).
  const int prow = lane >> 3;               // 0..7
  const int pslot = lane & 7;
  const int gslot = pslot ^ prow;
  const __hip_bfloat16* aS = A  + (size_t)(m0 + w * 8 + prow) * K + gslot * 8;
  const __hip_bfloat16* bS = Bt + (size_t)(n0 + w * 8 + prow) * K + gslot * 8;
  const size_t K32g = (size_t)32 * K;       // 32-row pass stride (global)
  const int ldsw = w << 9;                  // w*512 elems (8 rows x 64)

  // per-wave loads per stage: 4 (A) + BPASS (B)
  auto stage = [&](int buf, int k0) {
    __hip_bfloat16* Ab = As + buf * ABUF + ldsw;
    __hip_bfloat16* Bb = Bs + buf * BBUF + ldsw;
#pragma unroll
    for (int p = 0; p < 4; p++)
      gl2lds16(Ab + p * 2048, aS + k0 + p * K32g);
#pragma unroll
    for (int p = 0; p < BPASS; p++)
      gl2lds16(Bb + p * 2048, bS + k0 + p * K32g);
  };

  // read-side swizzled slots (per-lane constants)
  const int rx = lr & 7;
  const int arow = wr * 64 + lr;            // + i*16
  const int brow = wc * (BN / 2) + lr;      // + j*16

  const int nt = K >> 6;                    // BK=64 tiles (12 or 48)
  stage(0, 0);
  stage(1, 64);

  for (int t = 0; t < nt; ++t) {
    const int cur = t & 1;
    // counted wait: tile t's own loads done (= 4+BPASS of t+1 in flight)
    if (t == nt - 1) {
      asm volatile("s_waitcnt vmcnt(0)" ::: "memory");
    } else {
      if constexpr (BN == 192)      asm volatile("s_waitcnt vmcnt(10)" ::: "memory");
      else if constexpr (BN == 128) asm volatile("s_waitcnt vmcnt(8)" ::: "memory");
      else                          asm volatile("s_waitcnt vmcnt(7)" ::: "memory");
    }
    asm volatile("s_barrier" ::: "memory");          // all waves: tile t ready

    const __hip_bfloat16* Ab = As + cur * ABUF;
    const __hip_bfloat16* Bb = Bs + cur * BBUF;
    bf16x8s af[2][4], bq[2][NF];
#pragma unroll
    for (int kk = 0; kk < 2; kk++) {
      const int sl = ((kk * 4 + kg) ^ rx) * 8;
#pragma unroll
      for (int i = 0; i < 4; i++)
        af[kk][i] = *reinterpret_cast<const bf16x8s*>(&Ab[(arow + i * 16) * 64 + sl]);
#pragma unroll
      for (int j = 0; j < NF; j++)
        bq[kk][j] = *reinterpret_cast<const bf16x8s*>(&Bb[(brow + j * 16) * 64 + sl]);
    }
    asm volatile("s_waitcnt lgkmcnt(0)" ::: "memory");  // frags in regs
    asm volatile("s_barrier" ::: "memory");             // all waves done reading

    if (t + 2 < nt) stage(cur, (t + 2) << 6);  // overwrite just-read buffer

#pragma unroll
    for (int kk = 0; kk < 2; kk++)
#pragma unroll
      for (int i = 0; i < 4; i++)
#pragma unroll
        for (int j = 0; j < NF; j++)
          acc[i][j] = __builtin_amdgcn_mfma_f32_16x16x32_bf16(
              af[kk][i], bq[kk][j], acc[i][j], 0, 0, 0);
  }

  // ---- epilogue: dump activated tile to LDS, then coalesced write-out ----
  __hip_bfloat16* Ct = smem;
#pragma unroll
  for (int i = 0; i < 4; i++)
#pragma unroll
    for (int j = 0; j < NF; j++) {
      int cl = wc * (BN / 2) + j * 16 + lr;      // col within tile
      float bv = bias[n0 + cl];
#pragma unroll
      for (int r = 0; r < 4; r++) {
        int rl = wr * 64 + i * 16 + kg * 4 + r;  // row within tile
        float v = acc[i][j][r] + bv;
        if (ACT == 1) v = 1.f / (1.f + __expf(-v));
        else if (ACT == 2) {
          float x = v;
          float z = 1.5957691216057308f * (x + 0.044715f * x * x * x);
          v = x / (1.f + __expf(-z));
        }
        if (RADD) v += __bfloat162float(R[(size_t)(m0 + rl) * N + n0 + cl]);
        Ct[rl * CP + cl] = __float2bfloat16(v);
      }
    }
  __syncthreads();

  // coalesced write-out: 16B chunks, 16 consecutive lanes = 256B runs
  constexpr int CPR = BN / 8;               // 16B chunks per row (12/16/24)
  constexpr int NPASS = 128 * CPR / 256;    // 6/8/12 passes
#pragma unroll
  for (int p = 0; p < NPASS; ++p) {
    int idx = p * 256 + tid;
    int row = idx / CPR;
    int ch  = idx - row * CPR;
    uint4 d = *reinterpret_cast<const uint4*>(&Ct[row * CP + ch * 8]);
    *reinterpret_cast<uint4*>(&Cb[(size_t)(m0 + row) * N + n0 + ch * 8]) = d;
  }
}

// ---------------------------------------------------------------------------
extern "C" void kernel_launch(void* const* d_in, const int* in_sizes, int n_in,
                              void* d_out, int out_size, void* d_ws, size_t ws_size,
                              hipStream_t stream)
{
  const int*   ids  = (const int*)d_in[0];
  const float* wemb = (const float*)d_in[1];
  const float* pemb = (const float*)d_in[2];
  const float* elns = (const float*)d_in[3];
  const float* elnb = (const float*)d_in[4];
  const float* retW = (const float*)d_in[5];
  const float* retb = (const float*)d_in[6];
  const float* ln1s = (const float*)d_in[7];
  const float* ln1b = (const float*)d_in[8];
  const float* W1   = (const float*)d_in[9];
  const float* b1   = (const float*)d_in[10];
  const float* W2   = (const float*)d_in[11];
  const float* b2   = (const float*)d_in[12];
  const float* ln2s = (const float*)d_in[13];
  const float* ln2b = (const float*)d_in[14];
  const float* fins = (const float*)d_in[15];
  const float* finb = (const float*)d_in[16];
  float* out = (float*)d_out;

  char* ws = (char*)d_ws;
  size_t off = 0;
  __hip_bfloat16* retWt = (__hip_bfloat16*)(ws + off); off += (size_t)NL * HD * HD * 2;
  __hip_bfloat16* W1t   = (__hip_bfloat16*)(ws + off); off += (size_t)NL * HD * ID * 2;
  __hip_bfloat16* W2t   = (__hip_bfloat16*)(ws + off); off += (size_t)NL * ID * HD * 2;
  __hip_bfloat16* hb    = (__hip_bfloat16*)(ws + off); off += (size_t)ROWS * HD * 2;  // residual h
  __hip_bfloat16* h1b   = (__hip_bfloat16*)(ws + off); off += (size_t)ROWS * HD * 2;  // h1
  __hip_bfloat16* yb    = (__hip_bfloat16*)(ws + off); off += (size_t)ROWS * HD * 2;  // h1+ffn2
  __hip_bfloat16* gb    = (__hip_bfloat16*)(ws + off); off += (size_t)ROWS * ID * 2;  // s / gelu out
  __hip_bfloat16* sb = gb;   // sigmoid out aliases gb (consumed before FFN1 rewrites)

  // all three weight transposes in one launch (20736 tiles)
  transpose_all_kernel<<<dim3(20736), dim3(32, 8), 0, stream>>>(
      retW, W1, W2, retWt, W1t, W2t);

  embed_ln_kernel<<<ROWS/4, 256, 0, stream>>>(ids, wemb, pemb, elns, elnb, hb);

  for (int l = 0; l < NL; l++) {
    // s = sigmoid(h @ retW + rb) -> sb (bf16). BN=192 (256 blocks = 1/CU)
    gemm_mfma_kernel<192, 1, 0><<<dim3(ROWS/128, HD/192), 256, 0, stream>>>(
        hb, retWt + (size_t)l * HD * HD, retb + (size_t)l * HD,
        nullptr, sb, ROWS, HD, HD);
    // h1 = LN(h + retention(s))  [fused scan+LN, warm-up 16]
    scan_ln_kernel<<<NB * (SL/32), 768, 0, stream>>>(sb, hb,
        ln1s + (size_t)l * HD, ln1b + (size_t)l * HD, h1b);
    // g = gelu(h1 @ W1 + b1) -> gb (bf16). BN=192 (1024 blocks = 4/CU)
    gemm_mfma_kernel<192, 2, 0><<<dim3(ROWS/128, ID/192), 256, 0, stream>>>(
        h1b, W1t + (size_t)l * ID * HD, b1 + (size_t)l * ID,
        nullptr, gb, ROWS, ID, HD);
    // y = h1 + (g @ W2 + b2) -> yb (bf16). BN=192 (256 blocks = 1/CU)
    gemm_mfma_kernel<192, 0, 1><<<dim3(ROWS/128, HD/192), 256, 0, stream>>>(
        gb, W2t + (size_t)l * HD * ID, b2 + (size_t)l * HD,
        h1b, yb, ROWS, HD, ID);
    if (l < NL - 1) {
      // h = LN(y)
      ln_row_kernel<0><<<ROWS/4, 256, 0, stream>>>(yb,
          ln2s + (size_t)l * HD, ln2b + (size_t)l * HD, hb, nullptr);
    } else {
      // last layer: out = LNf(bf16(LN2(y))) fused — skips hb round-trip
      ln2_final_kernel<<<ROWS/4, 256, 0, stream>>>(yb,
          ln2s + (size_t)l * HD, ln2b + (size_t)l * HD, fins, finb, out);
    }
  }
}

// Round 23
// 531.110 us; speedup vs baseline: 1.0568x; 1.0568x over previous
//
#include <hip/hip_runtime.h>
#include <hip/hip_bf16.h>
#include <cstdint>
#include <cstddef>

// Problem dims
#define HD   768
#define ID   3072
#define NB   4
#define SL   2048
#define NL   4
#define ROWS (NB*SL)   // 8192

typedef __attribute__((ext_vector_type(8))) short bf16x8s;
typedef __attribute__((ext_vector_type(4))) float f32x4;
typedef __attribute__((ext_vector_type(4))) unsigned short u16x4;

typedef __attribute__((address_space(1))) const unsigned int g_as1_u32;
typedef __attribute__((address_space(3))) unsigned int lds_as3_u32;

// async 16B/lane global->LDS copy (wave-uniform LDS base + lane*16)
__device__ __forceinline__ void gl2lds16(__hip_bfloat16* l, const __hip_bfloat16* g) {
  __builtin_amdgcn_global_load_lds((g_as1_u32*)g, (lds_as3_u32*)l, 16, 0, 0);
}

__device__ __forceinline__ float bfu2f(unsigned short u) {
  return __uint_as_float((unsigned int)u << 16);
}
__device__ __forceinline__ unsigned short f2bfu(float f) {
  __hip_bfloat16 h = __float2bfloat16(f);
  return *reinterpret_cast<unsigned short*>(&h);
}

// ---------------------------------------------------------------------------
// Wave-per-row LayerNorm: block=256 (4 waves), wave w does row blockIdx*4+w.
// ---------------------------------------------------------------------------
template <int OUTF32>
__global__ __launch_bounds__(256) void ln_row_kernel(
    const __hip_bfloat16* __restrict__ x,
    const float* __restrict__ scale, const float* __restrict__ bias,
    __hip_bfloat16* __restrict__ ob, float* __restrict__ of)
{
  const int w = threadIdx.x >> 6, lane = threadIdx.x & 63;
  const size_t row = (size_t)blockIdx.x * 4 + w;
  const __hip_bfloat16* xr = x + row * HD;
  float v[12];
#pragma unroll
  for (int c = 0; c < 3; c++) {
    u16x4 u = *reinterpret_cast<const u16x4*>(xr + c * 256 + lane * 4);
#pragma unroll
    for (int i = 0; i < 4; i++) v[c * 4 + i] = bfu2f(u[i]);
  }
  float s = 0.f;
#pragma unroll
  for (int i = 0; i < 12; i++) s += v[i];
#pragma unroll
  for (int m = 1; m < 64; m <<= 1) s += __shfl_xor(s, m);
  float mean = s * (1.0f / 768.0f);
  float q = 0.f;
#pragma unroll
  for (int i = 0; i < 12; i++) { float d = v[i] - mean; q += d * d; }
#pragma unroll
  for (int m = 1; m < 64; m <<= 1) q += __shfl_xor(q, m);
  float rstd = rsqrtf(q * (1.0f / 768.0f) + 1e-5f);
#pragma unroll
  for (int c = 0; c < 3; c++) {
    int j0 = c * 256 + lane * 4;
    if (OUTF32) {
      f32x4 o;
#pragma unroll
      for (int i = 0; i < 4; i++)
        o[i] = (v[c * 4 + i] - mean) * rstd * scale[j0 + i] + bias[j0 + i];
      *reinterpret_cast<f32x4*>(of + row * HD + j0) = o;
    } else {
      u16x4 o;
#pragma unroll
      for (int i = 0; i < 4; i++)
        o[i] = f2bfu((v[c * 4 + i] - mean) * rstd * scale[j0 + i] + bias[j0 + i]);
      *reinterpret_cast<u16x4*>(ob + row * HD + j0) = o;
    }
  }
}

// ---------------------------------------------------------------------------
// Fused LN2 + final LN (last layer only): out = LNf(bf16(LN2(y))).
// ---------------------------------------------------------------------------
__global__ __launch_bounds__(256) void ln2_final_kernel(
    const __hip_bfloat16* __restrict__ y,
    const float* __restrict__ s2, const float* __restrict__ b2,
    const float* __restrict__ fs, const float* __restrict__ fb,
    float* __restrict__ out)
{
  const int w = threadIdx.x >> 6, lane = threadIdx.x & 63;
  const size_t row = (size_t)blockIdx.x * 4 + w;
  const __hip_bfloat16* xr = y + row * HD;
  float v[12];
#pragma unroll
  for (int c = 0; c < 3; c++) {
    u16x4 u = *reinterpret_cast<const u16x4*>(xr + c * 256 + lane * 4);
#pragma unroll
    for (int i = 0; i < 4; i++) v[c * 4 + i] = bfu2f(u[i]);
  }
  float s = 0.f;
#pragma unroll
  for (int i = 0; i < 12; i++) s += v[i];
#pragma unroll
  for (int m = 1; m < 64; m <<= 1) s += __shfl_xor(s, m);
  float mean = s * (1.0f / 768.0f);
  float q = 0.f;
#pragma unroll
  for (int i = 0; i < 12; i++) { float d = v[i] - mean; q += d * d; }
#pragma unroll
  for (int m = 1; m < 64; m <<= 1) q += __shfl_xor(q, m);
  float rstd = rsqrtf(q * (1.0f / 768.0f) + 1e-5f);
  // LN2 result, rounded to bf16 exactly as the unfused path stored it
  float t[12];
#pragma unroll
  for (int c = 0; c < 3; c++) {
    int j0 = c * 256 + lane * 4;
#pragma unroll
    for (int i = 0; i < 4; i++)
      t[c * 4 + i] = bfu2f(f2bfu((v[c * 4 + i] - mean) * rstd * s2[j0 + i] + b2[j0 + i]));
  }
  // final LN over t
  float s2m = 0.f;
#pragma unroll
  for (int i = 0; i < 12; i++) s2m += t[i];
#pragma unroll
  for (int m = 1; m < 64; m <<= 1) s2m += __shfl_xor(s2m, m);
  float mean2 = s2m * (1.0f / 768.0f);
  float q2 = 0.f;
#pragma unroll
  for (int i = 0; i < 12; i++) { float d = t[i] - mean2; q2 += d * d; }
#pragma unroll
  for (int m = 1; m < 64; m <<= 1) q2 += __shfl_xor(q2, m);
  float rstd2 = rsqrtf(q2 * (1.0f / 768.0f) + 1e-5f);
#pragma unroll
  for (int c = 0; c < 3; c++) {
    int j0 = c * 256 + lane * 4;
    f32x4 o;
#pragma unroll
    for (int i = 0; i < 4; i++)
      o[i] = (t[c * 4 + i] - mean2) * rstd2 * fs[j0 + i] + fb[j0 + i];
    *reinterpret_cast<f32x4*>(out + row * HD + j0) = o;
  }
}

// embedding gather + pos add + LN (wave-per-row), writes bf16
__global__ __launch_bounds__(256) void embed_ln_kernel(
    const int* __restrict__ ids, const float* __restrict__ wemb,
    const float* __restrict__ pemb,
    const float* __restrict__ scale, const float* __restrict__ bias,
    __hip_bfloat16* __restrict__ ob)
{
  const int w = threadIdx.x >> 6, lane = threadIdx.x & 63;
  const size_t row = (size_t)blockIdx.x * 4 + w;
  const int t = (int)(row & (SL - 1));
  const int id = ids[row];
  float v[12];
#pragma unroll
  for (int c = 0; c < 3; c++) {
    int j0 = c * 256 + lane * 4;
    f32x4 a = *reinterpret_cast<const f32x4*>(wemb + (size_t)id * HD + j0);
    f32x4 p = *reinterpret_cast<const f32x4*>(pemb + (size_t)t * HD + j0);
#pragma unroll
    for (int i = 0; i < 4; i++) v[c * 4 + i] = a[i] + p[i];
  }
  float s = 0.f;
#pragma unroll
  for (int i = 0; i < 12; i++) s += v[i];
#pragma unroll
  for (int m = 1; m < 64; m <<= 1) s += __shfl_xor(s, m);
  float mean = s * (1.0f / 768.0f);
  float q = 0.f;
#pragma unroll
  for (int i = 0; i < 12; i++) { float d = v[i] - mean; q += d * d; }
#pragma unroll
  for (int m = 1; m < 64; m <<= 1) q += __shfl_xor(q, m);
  float rstd = rsqrtf(q * (1.0f / 768.0f) + 1e-5f);
#pragma unroll
  for (int c = 0; c < 3; c++) {
    int j0 = c * 256 + lane * 4;
    u16x4 o;
#pragma unroll
    for (int i = 0; i < 4; i++)
      o[i] = f2bfu((v[c * 4 + i] - mean) * rstd * scale[j0 + i] + bias[j0 + i]);
    *reinterpret_cast<u16x4*>(ob + row * HD + j0) = o;
  }
}

// ---------------------------------------------------------------------------
// Merged weight transpose + f32->bf16 for retW, W1, W2 (single launch).
// ---------------------------------------------------------------------------
__global__ __launch_bounds__(256) void transpose_all_kernel(
    const float* __restrict__ retW, const float* __restrict__ W1,
    const float* __restrict__ W2,
    __hip_bfloat16* __restrict__ retWt, __hip_bfloat16* __restrict__ W1t,
    __hip_bfloat16* __restrict__ W2t)
{
  __shared__ float tile[32][33];
  int id = blockIdx.x;
  const float* in; __hip_bfloat16* outp; int K, N, n0, k0;
  if (id < 2304) {                          // retW [l][K=HD][N=HD]
    int l = id / 576, rem = id % 576;
    K = HD; N = HD;
    n0 = (rem % 24) * 32; k0 = (rem / 24) * 32;
    in = retW + (size_t)l * HD * HD; outp = retWt + (size_t)l * HD * HD;
  } else if (id < 2304 + 9216) {            // W1 [l][K=HD][N=ID]
    int id2 = id - 2304;
    int l = id2 / 2304, rem = id2 % 2304;
    K = HD; N = ID;
    n0 = (rem % 96) * 32; k0 = (rem / 96) * 32;
    in = W1 + (size_t)l * HD * ID; outp = W1t + (size_t)l * HD * ID;
  } else {                                  // W2 [l][K=ID][N=HD]
    int id2 = id - 2304 - 9216;
    int l = id2 / 2304, rem = id2 % 2304;
    K = ID; N = HD;
    n0 = (rem % 24) * 32; k0 = (rem / 24) * 32;
    in = W2 + (size_t)l * ID * HD; outp = W2t + (size_t)l * ID * HD;
  }
  int tx = threadIdx.x, ty = threadIdx.y;   // (32, 8)
#pragma unroll
  for (int i = 0; i < 4; i++)
    tile[ty + i * 8][tx] = in[(size_t)(k0 + ty + i * 8) * N + n0 + tx];
  __syncthreads();
#pragma unroll
  for (int i = 0; i < 4; i++)
    outp[(size_t)(n0 + ty + i * 8) * K + k0 + tx] = __float2bfloat16(tile[tx][ty + i * 8]);
}

// ---------------------------------------------------------------------------
// Fused retention scan + residual + LN1 (warm-up 16: 0.5^16 ~ 1.5e-5).
// ---------------------------------------------------------------------------
__global__ __launch_bounds__(768) void scan_ln_kernel(
    const __hip_bfloat16* __restrict__ s,
    const __hip_bfloat16* __restrict__ h,
    const float* __restrict__ scale, const float* __restrict__ bias,
    __hip_bfloat16* __restrict__ h1)
{
  __shared__ __hip_bfloat16 zt[32][HD];     // 48 KB
  const int col = threadIdx.x;              // 0..767
  const int nchunk = SL / 32;               // 64
  const int c = blockIdx.x & (nchunk - 1);
  const int b = blockIdx.x / nchunk;
  const int tstart = c * 32;
  int t0 = tstart - 16; if (t0 < 0) t0 = 0;
  const __hip_bfloat16* sp = s + (size_t)b * SL * HD + col;
  const __hip_bfloat16* hp = h + (size_t)b * SL * HD + col;
  float acc = 0.f;
#pragma unroll 8
  for (int t = t0; t < tstart; ++t)
    acc = 0.5f * (__bfloat162float(sp[(size_t)t * HD]) + acc);
#pragma unroll 8
  for (int tt = 0; tt < 32; ++tt) {
    int t = tstart + tt;
    acc = 0.5f * (__bfloat162float(sp[(size_t)t * HD]) + acc);
    zt[tt][col] = __float2bfloat16(acc + __bfloat162float(hp[(size_t)t * HD]));
  }
  __syncthreads();
  // LN phase: 12 waves, wave wv handles rows wv, wv+12, wv+24 (<32)
  const int wv = threadIdx.x >> 6, lane = threadIdx.x & 63;
  for (int row = wv; row < 32; row += 12) {
    float v[12];
#pragma unroll
    for (int cc = 0; cc < 3; cc++) {
      u16x4 u = *reinterpret_cast<const u16x4*>(&zt[row][cc * 256 + lane * 4]);
#pragma unroll
      for (int i = 0; i < 4; i++) v[cc * 4 + i] = bfu2f(u[i]);
    }
    float sm = 0.f;
#pragma unroll
    for (int i = 0; i < 12; i++) sm += v[i];
#pragma unroll
    for (int m = 1; m < 64; m <<= 1) sm += __shfl_xor(sm, m);
    float mean = sm * (1.0f / 768.0f);
    float q = 0.f;
#pragma unroll
    for (int i = 0; i < 12; i++) { float d = v[i] - mean; q += d * d; }
#pragma unroll
    for (int m = 1; m < 64; m <<= 1) q += __shfl_xor(q, m);
    float rstd = rsqrtf(q * (1.0f / 768.0f) + 1e-5f);
    __hip_bfloat16* orow = h1 + ((size_t)b * SL + tstart + row) * HD;
#pragma unroll
    for (int cc = 0; cc < 3; cc++) {
      int j0 = cc * 256 + lane * 4;
      u16x4 o;
#pragma unroll
      for (int i = 0; i < 4; i++)
        o[i] = f2bfu((v[cc * 4 + i] - mean) * rstd * scale[j0 + i] + bias[j0 + i]);
      *reinterpret_cast<u16x4*>(orow + j0) = o;
    }
  }
}

// ---------------------------------------------------------------------------
// Counted-vmcnt pipelined MFMA GEMM (r12 schedule) + coalesced LDS epilogue.
// BM=128, 4 waves (256 thr), BK=64, 2 LDS buffers, 2 blocks/CU.
// BN in {96,128,192}; per-wave N sub-tile = BN/2 (NF = BN/32 frags).
// BN=192 pays only when grid >= 2 blocks/CU (FFN1); N=768 GEMMs use BN=96.
// ---------------------------------------------------------------------------
template <int BN, int ACT, int RADD>
__global__ __launch_bounds__(256, 2) void gemm_mfma_kernel(
    const __hip_bfloat16* __restrict__ A,
    const __hip_bfloat16* __restrict__ Bt,
    const float* __restrict__ bias,
    const __hip_bfloat16* __restrict__ R,
    __hip_bfloat16* __restrict__ Cb,
    int M, int N, int K)
{
  constexpr int NF = BN / 32;               // N-frags per wave: 3,4,6
  constexpr int BPASS = BN / 32;            // B staging passes (32 rows each)
  constexpr int ABUF = 128 * 64;            // A buffer elems (16KB)
  constexpr int BBUF = BN * 64;             // B buffer elems (12/16/24KB)
  constexpr int CP = BN + 8;                // padded C-tile stride (elems)
  static_assert(128 * CP <= 2 * ABUF + 2 * BBUF, "C tile must fit in smem");
  __shared__ __align__(16) __hip_bfloat16 smem[2 * ABUF + 2 * BBUF];
  __hip_bfloat16* As = smem;
  __hip_bfloat16* Bs = smem + 2 * ABUF;
  const int m0 = blockIdx.x * 128;
  const int n0 = blockIdx.y * BN;
  const int tid  = threadIdx.x;
  const int lane = tid & 63;
  const int w    = tid >> 6;                // wave 0..3
  const int wr   = w >> 1;                  // 0..1 (M half, 64 rows)
  const int wc   = w & 1;                   // 0..1 (N half)
  const int lr   = lane & 15;
  const int kg   = lane >> 4;               // 0..3

  f32x4 acc[4][NF];
#pragma unroll
  for (int i = 0; i < 4; i++)
#pragma unroll
    for (int j = 0; j < NF; j++) acc[i][j] = (f32x4){0.f, 0.f, 0.f, 0.f};

  // staging: pass = 256 thr x 16B = 32 rows x 128B. Wave w rows w*8..w*8+7.
  // lane l: row w*8 + l/8, LDS slot l%8, global k-slot (l%8)^(l/8).
  const int prow = lane >> 3;               // 0..7
  const int pslot = lane & 7;
  const int gslot = pslot ^ prow;
  const __hip_bfloat16* aS = A  + (size_t)(m0 + w * 8 + prow) * K + gslot * 8;
  const __hip_bfloat16* bS = Bt + (size_t)(n0 + w * 8 + prow) * K + gslot * 8;
  const size_t K32g = (size_t)32 * K;       // 32-row pass stride (global)
  const int ldsw = w << 9;                  // w*512 elems (8 rows x 64)

  // per-wave loads per stage: 4 (A) + BPASS (B)
  auto stage = [&](int buf, int k0) {
    __hip_bfloat16* Ab = As + buf * ABUF + ldsw;
    __hip_bfloat16* Bb = Bs + buf * BBUF + ldsw;
#pragma unroll
    for (int p = 0; p < 4; p++)
      gl2lds16(Ab + p * 2048, aS + k0 + p * K32g);
#pragma unroll
    for (int p = 0; p < BPASS; p++)
      gl2lds16(Bb + p * 2048, bS + k0 + p * K32g);
  };

  // read-side swizzled slots (per-lane constants)
  const int rx = lr & 7;
  const int arow = wr * 64 + lr;            // + i*16
  const int brow = wc * (BN / 2) + lr;      // + j*16

  const int nt = K >> 6;                    // BK=64 tiles (12 or 48)
  stage(0, 0);
  stage(1, 64);

  for (int t = 0; t < nt; ++t) {
    const int cur = t & 1;
    // counted wait: tile t's own loads done (= 4+BPASS of t+1 in flight)
    if (t == nt - 1) {
      asm volatile("s_waitcnt vmcnt(0)" ::: "memory");
    } else {
      if constexpr (BN == 192)      asm volatile("s_waitcnt vmcnt(10)" ::: "memory");
      else if constexpr (BN == 128) asm volatile("s_waitcnt vmcnt(8)" ::: "memory");
      else                          asm volatile("s_waitcnt vmcnt(7)" ::: "memory");
    }
    asm volatile("s_barrier" ::: "memory");          // all waves: tile t ready

    const __hip_bfloat16* Ab = As + cur * ABUF;
    const __hip_bfloat16* Bb = Bs + cur * BBUF;
    bf16x8s af[2][4], bq[2][NF];
#pragma unroll
    for (int kk = 0; kk < 2; kk++) {
      const int sl = ((kk * 4 + kg) ^ rx) * 8;
#pragma unroll
      for (int i = 0; i < 4; i++)
        af[kk][i] = *reinterpret_cast<const bf16x8s*>(&Ab[(arow + i * 16) * 64 + sl]);
#pragma unroll
      for (int j = 0; j < NF; j++)
        bq[kk][j] = *reinterpret_cast<const bf16x8s*>(&Bb[(brow + j * 16) * 64 + sl]);
    }
    asm volatile("s_waitcnt lgkmcnt(0)" ::: "memory");  // frags in regs
    asm volatile("s_barrier" ::: "memory");             // all waves done reading

    if (t + 2 < nt) stage(cur, (t + 2) << 6);  // overwrite just-read buffer

#pragma unroll
    for (int kk = 0; kk < 2; kk++)
#pragma unroll
      for (int i = 0; i < 4; i++)
#pragma unroll
        for (int j = 0; j < NF; j++)
          acc[i][j] = __builtin_amdgcn_mfma_f32_16x16x32_bf16(
              af[kk][i], bq[kk][j], acc[i][j], 0, 0, 0);
  }

  // ---- epilogue: dump activated tile to LDS, then coalesced write-out ----
  __hip_bfloat16* Ct = smem;
#pragma unroll
  for (int i = 0; i < 4; i++)
#pragma unroll
    for (int j = 0; j < NF; j++) {
      int cl = wc * (BN / 2) + j * 16 + lr;      // col within tile
      float bv = bias[n0 + cl];
#pragma unroll
      for (int r = 0; r < 4; r++) {
        int rl = wr * 64 + i * 16 + kg * 4 + r;  // row within tile
        float v = acc[i][j][r] + bv;
        if (ACT == 1) v = 1.f / (1.f + __expf(-v));
        else if (ACT == 2) {
          float x = v;
          float z = 1.5957691216057308f * (x + 0.044715f * x * x * x);
          v = x / (1.f + __expf(-z));
        }
        if (RADD) v += __bfloat162float(R[(size_t)(m0 + rl) * N + n0 + cl]);
        Ct[rl * CP + cl] = __float2bfloat16(v);
      }
    }
  __syncthreads();

  // coalesced write-out: 16B chunks, 16 consecutive lanes = 256B runs
  constexpr int CPR = BN / 8;               // 16B chunks per row (12/16/24)
  constexpr int NPASS = 128 * CPR / 256;    // 6/8/12 passes
#pragma unroll
  for (int p = 0; p < NPASS; ++p) {
    int idx = p * 256 + tid;
    int row = idx / CPR;
    int ch  = idx - row * CPR;
    uint4 d = *reinterpret_cast<const uint4*>(&Ct[row * CP + ch * 8]);
    *reinterpret_cast<uint4*>(&Cb[(size_t)(m0 + row) * N + n0 + ch * 8]) = d;
  }
}

// ---------------------------------------------------------------------------
extern "C" void kernel_launch(void* const* d_in, const int* in_sizes, int n_in,
                              void* d_out, int out_size, void* d_ws, size_t ws_size,
                              hipStream_t stream)
{
  const int*   ids  = (const int*)d_in[0];
  const float* wemb = (const float*)d_in[1];
  const float* pemb = (const float*)d_in[2];
  const float* elns = (const float*)d_in[3];
  const float* elnb = (const float*)d_in[4];
  const float* retW = (const float*)d_in[5];
  const float* retb = (const float*)d_in[6];
  const float* ln1s = (const float*)d_in[7];
  const float* ln1b = (const float*)d_in[8];
  const float* W1   = (const float*)d_in[9];
  const float* b1   = (const float*)d_in[10];
  const float* W2   = (const float*)d_in[11];
  const float* b2   = (const float*)d_in[12];
  const float* ln2s = (const float*)d_in[13];
  const float* ln2b = (const float*)d_in[14];
  const float* fins = (const float*)d_in[15];
  const float* finb = (const float*)d_in[16];
  float* out = (float*)d_out;

  char* ws = (char*)d_ws;
  size_t off = 0;
  __hip_bfloat16* retWt = (__hip_bfloat16*)(ws + off); off += (size_t)NL * HD * HD * 2;
  __hip_bfloat16* W1t   = (__hip_bfloat16*)(ws + off); off += (size_t)NL * HD * ID * 2;
  __hip_bfloat16* W2t   = (__hip_bfloat16*)(ws + off); off += (size_t)NL * ID * HD * 2;
  __hip_bfloat16* hb    = (__hip_bfloat16*)(ws + off); off += (size_t)ROWS * HD * 2;  // residual h
  __hip_bfloat16* h1b   = (__hip_bfloat16*)(ws + off); off += (size_t)ROWS * HD * 2;  // h1
  __hip_bfloat16* yb    = (__hip_bfloat16*)(ws + off); off += (size_t)ROWS * HD * 2;  // h1+ffn2
  __hip_bfloat16* gb    = (__hip_bfloat16*)(ws + off); off += (size_t)ROWS * ID * 2;  // s / gelu out
  __hip_bfloat16* sb = gb;   // sigmoid out aliases gb (consumed before FFN1 rewrites)

  // all three weight transposes in one launch (20736 tiles)
  transpose_all_kernel<<<dim3(20736), dim3(32, 8), 0, stream>>>(
      retW, W1, W2, retWt, W1t, W2t);

  embed_ln_kernel<<<ROWS/4, 256, 0, stream>>>(ids, wemb, pemb, elns, elnb, hb);

  for (int l = 0; l < NL; l++) {
    // s = sigmoid(h @ retW + rb) -> sb (bf16). BN=96 (512 blocks = 2/CU)
    gemm_mfma_kernel<96, 1, 0><<<dim3(ROWS/128, HD/96), 256, 0, stream>>>(
        hb, retWt + (size_t)l * HD * HD, retb + (size_t)l * HD,
        nullptr, sb, ROWS, HD, HD);
    // h1 = LN(h + retention(s))  [fused scan+LN, warm-up 16]
    scan_ln_kernel<<<NB * (SL/32), 768, 0, stream>>>(sb, hb,
        ln1s + (size_t)l * HD, ln1b + (size_t)l * HD, h1b);
    // g = gelu(h1 @ W1 + b1) -> gb (bf16). BN=192 (1024 blocks = 4/CU)
    gemm_mfma_kernel<192, 2, 0><<<dim3(ROWS/128, ID/192), 256, 0, stream>>>(
        h1b, W1t + (size_t)l * ID * HD, b1 + (size_t)l * ID,
        nullptr, gb, ROWS, ID, HD);
    // y = h1 + (g @ W2 + b2) -> yb (bf16). BN=96 (512 blocks = 2/CU)
    gemm_mfma_kernel<96, 0, 1><<<dim3(ROWS/128, HD/96), 256, 0, stream>>>(
        gb, W2t + (size_t)l * HD * ID, b2 + (size_t)l * HD,
        h1b, yb, ROWS, HD, ID);
    if (l < NL - 1) {
      // h = LN(y)
      ln_row_kernel<0><<<ROWS/4, 256, 0, stream>>>(yb,
          ln2s + (size_t)l * HD, ln2b + (size_t)l * HD, hb, nullptr);
    } else {
      // last layer: out = LNf(bf16(LN2(y))) fused — skips hb round-trip
      ln2_final_kernel<<<ROWS/4, 256, 0, stream>>>(yb,
          ln2s + (size_t)l * HD, ln2b + (size_t)l * HD, fins, finb, out);
    }
  }
}

// Round 24
// 529.887 us; speedup vs baseline: 1.0593x; 1.0023x over previous
//
#include <hip/hip_runtime.h>
#include <hip/hip_bf16.h>
#include <cstdint>
#include <cstddef>

// Problem dims
#define HD   768
#define ID   3072
#define NB   4
#define SL   2048
#define NL   4
#define ROWS (NB*SL)   // 8192

typedef __attribute__((ext_vector_type(8))) short bf16x8s;
typedef __attribute__((ext_vector_type(4))) float f32x4;
typedef __attribute__((ext_vector_type(4))) unsigned short u16x4;

typedef __attribute__((address_space(1))) const unsigned int g_as1_u32;
typedef __attribute__((address_space(3))) unsigned int lds_as3_u32;

// async 16B/lane global->LDS copy (wave-uniform LDS base + lane*16)
__device__ __forceinline__ void gl2lds16(__hip_bfloat16* l, const __hip_bfloat16* g) {
  __builtin_amdgcn_global_load_lds((g_as1_u32*)g, (lds_as3_u32*)l, 16, 0, 0);
}

__device__ __forceinline__ float bfu2f(unsigned short u) {
  return __uint_as_float((unsigned int)u << 16);
}
__device__ __forceinline__ unsigned short f2bfu(float f) {
  __hip_bfloat16 h = __float2bfloat16(f);
  return *reinterpret_cast<unsigned short*>(&h);
}

// ---------------------------------------------------------------------------
// Wave-per-row LayerNorm: block=256 (4 waves), wave w does row blockIdx*4+w.
// ---------------------------------------------------------------------------
template <int OUTF32>
__global__ __launch_bounds__(256) void ln_row_kernel(
    const __hip_bfloat16* __restrict__ x,
    const float* __restrict__ scale, const float* __restrict__ bias,
    __hip_bfloat16* __restrict__ ob, float* __restrict__ of)
{
  const int w = threadIdx.x >> 6, lane = threadIdx.x & 63;
  const size_t row = (size_t)blockIdx.x * 4 + w;
  const __hip_bfloat16* xr = x + row * HD;
  float v[12];
#pragma unroll
  for (int c = 0; c < 3; c++) {
    u16x4 u = *reinterpret_cast<const u16x4*>(xr + c * 256 + lane * 4);
#pragma unroll
    for (int i = 0; i < 4; i++) v[c * 4 + i] = bfu2f(u[i]);
  }
  float s = 0.f;
#pragma unroll
  for (int i = 0; i < 12; i++) s += v[i];
#pragma unroll
  for (int m = 1; m < 64; m <<= 1) s += __shfl_xor(s, m);
  float mean = s * (1.0f / 768.0f);
  float q = 0.f;
#pragma unroll
  for (int i = 0; i < 12; i++) { float d = v[i] - mean; q += d * d; }
#pragma unroll
  for (int m = 1; m < 64; m <<= 1) q += __shfl_xor(q, m);
  float rstd = rsqrtf(q * (1.0f / 768.0f) + 1e-5f);
#pragma unroll
  for (int c = 0; c < 3; c++) {
    int j0 = c * 256 + lane * 4;
    if (OUTF32) {
      f32x4 o;
#pragma unroll
      for (int i = 0; i < 4; i++)
        o[i] = (v[c * 4 + i] - mean) * rstd * scale[j0 + i] + bias[j0 + i];
      *reinterpret_cast<f32x4*>(of + row * HD + j0) = o;
    } else {
      u16x4 o;
#pragma unroll
      for (int i = 0; i < 4; i++)
        o[i] = f2bfu((v[c * 4 + i] - mean) * rstd * scale[j0 + i] + bias[j0 + i]);
      *reinterpret_cast<u16x4*>(ob + row * HD + j0) = o;
    }
  }
}

// ---------------------------------------------------------------------------
// Fused LN2 + final LN (last layer only): out = LNf(bf16(LN2(y))).
// ---------------------------------------------------------------------------
__global__ __launch_bounds__(256) void ln2_final_kernel(
    const __hip_bfloat16* __restrict__ y,
    const float* __restrict__ s2, const float* __restrict__ b2,
    const float* __restrict__ fs, const float* __restrict__ fb,
    float* __restrict__ out)
{
  const int w = threadIdx.x >> 6, lane = threadIdx.x & 63;
  const size_t row = (size_t)blockIdx.x * 4 + w;
  const __hip_bfloat16* xr = y + row * HD;
  float v[12];
#pragma unroll
  for (int c = 0; c < 3; c++) {
    u16x4 u = *reinterpret_cast<const u16x4*>(xr + c * 256 + lane * 4);
#pragma unroll
    for (int i = 0; i < 4; i++) v[c * 4 + i] = bfu2f(u[i]);
  }
  float s = 0.f;
#pragma unroll
  for (int i = 0; i < 12; i++) s += v[i];
#pragma unroll
  for (int m = 1; m < 64; m <<= 1) s += __shfl_xor(s, m);
  float mean = s * (1.0f / 768.0f);
  float q = 0.f;
#pragma unroll
  for (int i = 0; i < 12; i++) { float d = v[i] - mean; q += d * d; }
#pragma unroll
  for (int m = 1; m < 64; m <<= 1) q += __shfl_xor(q, m);
  float rstd = rsqrtf(q * (1.0f / 768.0f) + 1e-5f);
  // LN2 result, rounded to bf16 exactly as the unfused path stored it
  float t[12];
#pragma unroll
  for (int c = 0; c < 3; c++) {
    int j0 = c * 256 + lane * 4;
#pragma unroll
    for (int i = 0; i < 4; i++)
      t[c * 4 + i] = bfu2f(f2bfu((v[c * 4 + i] - mean) * rstd * s2[j0 + i] + b2[j0 + i]));
  }
  // final LN over t
  float s2m = 0.f;
#pragma unroll
  for (int i = 0; i < 12; i++) s2m += t[i];
#pragma unroll
  for (int m = 1; m < 64; m <<= 1) s2m += __shfl_xor(s2m, m);
  float mean2 = s2m * (1.0f / 768.0f);
  float q2 = 0.f;
#pragma unroll
  for (int i = 0; i < 12; i++) { float d = t[i] - mean2; q2 += d * d; }
#pragma unroll
  for (int m = 1; m < 64; m <<= 1) q2 += __shfl_xor(q2, m);
  float rstd2 = rsqrtf(q2 * (1.0f / 768.0f) + 1e-5f);
#pragma unroll
  for (int c = 0; c < 3; c++) {
    int j0 = c * 256 + lane * 4;
    f32x4 o;
#pragma unroll
    for (int i = 0; i < 4; i++)
      o[i] = (t[c * 4 + i] - mean2) * rstd2 * fs[j0 + i] + fb[j0 + i];
    *reinterpret_cast<f32x4*>(out + row * HD + j0) = o;
  }
}

// ---------------------------------------------------------------------------
// Merged prologue: weight transposes (blocks 0..20735) + embed+LN
// (blocks 20736..22783) in ONE launch — both are mutually independent.
//   transpose: tile 32x32, flat 256 threads (tx=tid&31, ty=tid>>5)
//   embed: wave-per-row LN over rows (id-20736)*4 + w
// ---------------------------------------------------------------------------
__global__ __launch_bounds__(256) void prologue_kernel(
    const float* __restrict__ retW, const float* __restrict__ W1,
    const float* __restrict__ W2,
    __hip_bfloat16* __restrict__ retWt, __hip_bfloat16* __restrict__ W1t,
    __hip_bfloat16* __restrict__ W2t,
    const int* __restrict__ ids, const float* __restrict__ wemb,
    const float* __restrict__ pemb,
    const float* __restrict__ escale, const float* __restrict__ ebias,
    __hip_bfloat16* __restrict__ hb)
{
  __shared__ float tile[32][33];
  const int id = blockIdx.x;
  if (id < 20736) {
    // ---- transpose path ----
    const float* in; __hip_bfloat16* outp; int K, N, n0, k0;
    if (id < 2304) {                        // retW [l][K=HD][N=HD]
      int l = id / 576, rem = id % 576;
      K = HD; N = HD;
      n0 = (rem % 24) * 32; k0 = (rem / 24) * 32;
      in = retW + (size_t)l * HD * HD; outp = retWt + (size_t)l * HD * HD;
    } else if (id < 2304 + 9216) {          // W1 [l][K=HD][N=ID]
      int id2 = id - 2304;
      int l = id2 / 2304, rem = id2 % 2304;
      K = HD; N = ID;
      n0 = (rem % 96) * 32; k0 = (rem / 96) * 32;
      in = W1 + (size_t)l * HD * ID; outp = W1t + (size_t)l * HD * ID;
    } else {                                // W2 [l][K=ID][N=HD]
      int id2 = id - 2304 - 9216;
      int l = id2 / 2304, rem = id2 % 2304;
      K = ID; N = HD;
      n0 = (rem % 24) * 32; k0 = (rem / 24) * 32;
      in = W2 + (size_t)l * ID * HD; outp = W2t + (size_t)l * ID * HD;
    }
    const int tx = threadIdx.x & 31, ty = threadIdx.x >> 5;   // 32 x 8
#pragma unroll
    for (int i = 0; i < 4; i++)
      tile[ty + i * 8][tx] = in[(size_t)(k0 + ty + i * 8) * N + n0 + tx];
    __syncthreads();
#pragma unroll
    for (int i = 0; i < 4; i++)
      outp[(size_t)(n0 + ty + i * 8) * K + k0 + tx] = __float2bfloat16(tile[tx][ty + i * 8]);
  } else {
    // ---- embed + LN path ----
    const int w = threadIdx.x >> 6, lane = threadIdx.x & 63;
    const size_t row = (size_t)(id - 20736) * 4 + w;
    const int t = (int)(row & (SL - 1));
    const int tok = ids[row];
    float v[12];
#pragma unroll
    for (int c = 0; c < 3; c++) {
      int j0 = c * 256 + lane * 4;
      f32x4 a = *reinterpret_cast<const f32x4*>(wemb + (size_t)tok * HD + j0);
      f32x4 p = *reinterpret_cast<const f32x4*>(pemb + (size_t)t * HD + j0);
#pragma unroll
      for (int i = 0; i < 4; i++) v[c * 4 + i] = a[i] + p[i];
    }
    float s = 0.f;
#pragma unroll
    for (int i = 0; i < 12; i++) s += v[i];
#pragma unroll
    for (int m = 1; m < 64; m <<= 1) s += __shfl_xor(s, m);
    float mean = s * (1.0f / 768.0f);
    float q = 0.f;
#pragma unroll
    for (int i = 0; i < 12; i++) { float d = v[i] - mean; q += d * d; }
#pragma unroll
    for (int m = 1; m < 64; m <<= 1) q += __shfl_xor(q, m);
    float rstd = rsqrtf(q * (1.0f / 768.0f) + 1e-5f);
#pragma unroll
    for (int c = 0; c < 3; c++) {
      int j0 = c * 256 + lane * 4;
      u16x4 o;
#pragma unroll
      for (int i = 0; i < 4; i++)
        o[i] = f2bfu((v[c * 4 + i] - mean) * rstd * escale[j0 + i] + ebias[j0 + i]);
      *reinterpret_cast<u16x4*>(hb + row * HD + j0) = o;
    }
  }
}

// ---------------------------------------------------------------------------
// Fused retention scan + residual + LN1 (warm-up 16: 0.5^16 ~ 1.5e-5).
// ---------------------------------------------------------------------------
__global__ __launch_bounds__(768) void scan_ln_kernel(
    const __hip_bfloat16* __restrict__ s,
    const __hip_bfloat16* __restrict__ h,
    const float* __restrict__ scale, const float* __restrict__ bias,
    __hip_bfloat16* __restrict__ h1)
{
  __shared__ __hip_bfloat16 zt[32][HD];     // 48 KB
  const int col = threadIdx.x;              // 0..767
  const int nchunk = SL / 32;               // 64
  const int c = blockIdx.x & (nchunk - 1);
  const int b = blockIdx.x / nchunk;
  const int tstart = c * 32;
  int t0 = tstart - 16; if (t0 < 0) t0 = 0;
  const __hip_bfloat16* sp = s + (size_t)b * SL * HD + col;
  const __hip_bfloat16* hp = h + (size_t)b * SL * HD + col;
  float acc = 0.f;
#pragma unroll 8
  for (int t = t0; t < tstart; ++t)
    acc = 0.5f * (__bfloat162float(sp[(size_t)t * HD]) + acc);
#pragma unroll 8
  for (int tt = 0; tt < 32; ++tt) {
    int t = tstart + tt;
    acc = 0.5f * (__bfloat162float(sp[(size_t)t * HD]) + acc);
    zt[tt][col] = __float2bfloat16(acc + __bfloat162float(hp[(size_t)t * HD]));
  }
  __syncthreads();
  // LN phase: 12 waves, wave wv handles rows wv, wv+12, wv+24 (<32)
  const int wv = threadIdx.x >> 6, lane = threadIdx.x & 63;
  for (int row = wv; row < 32; row += 12) {
    float v[12];
#pragma unroll
    for (int cc = 0; cc < 3; cc++) {
      u16x4 u = *reinterpret_cast<const u16x4*>(&zt[row][cc * 256 + lane * 4]);
#pragma unroll
      for (int i = 0; i < 4; i++) v[cc * 4 + i] = bfu2f(u[i]);
    }
    float sm = 0.f;
#pragma unroll
    for (int i = 0; i < 12; i++) sm += v[i];
#pragma unroll
    for (int m = 1; m < 64; m <<= 1) sm += __shfl_xor(sm, m);
    float mean = sm * (1.0f / 768.0f);
    float q = 0.f;
#pragma unroll
    for (int i = 0; i < 12; i++) { float d = v[i] - mean; q += d * d; }
#pragma unroll
    for (int m = 1; m < 64; m <<= 1) q += __shfl_xor(q, m);
    float rstd = rsqrtf(q * (1.0f / 768.0f) + 1e-5f);
    __hip_bfloat16* orow = h1 + ((size_t)b * SL + tstart + row) * HD;
#pragma unroll
    for (int cc = 0; cc < 3; cc++) {
      int j0 = cc * 256 + lane * 4;
      u16x4 o;
#pragma unroll
      for (int i = 0; i < 4; i++)
        o[i] = f2bfu((v[cc * 4 + i] - mean) * rstd * scale[j0 + i] + bias[j0 + i]);
      *reinterpret_cast<u16x4*>(orow + j0) = o;
    }
  }
}

// ---------------------------------------------------------------------------
// Counted-vmcnt pipelined MFMA GEMM (r12 schedule) + coalesced LDS epilogue.
// BM=128, 4 waves (256 thr), BK=64, 2 LDS buffers, 2 blocks/CU.
// BN in {96,128,192}; per-wave N sub-tile = BN/2 (NF = BN/32 frags).
// BN=192 pays only when grid >= 2 blocks/CU (FFN1); N=768 GEMMs use BN=96.
// ---------------------------------------------------------------------------
template <int BN, int ACT, int RADD>
__global__ __launch_bounds__(256, 2) void gemm_mfma_kernel(
    const __hip_bfloat16* __restrict__ A,
    const __hip_bfloat16* __restrict__ Bt,
    const float* __restrict__ bias,
    const __hip_bfloat16* __restrict__ R,
    __hip_bfloat16* __restrict__ Cb,
    int M, int N, int K)
{
  constexpr int NF = BN / 32;               // N-frags per wave: 3,4,6
  constexpr int BPASS = BN / 32;            // B staging passes (32 rows each)
  constexpr int ABUF = 128 * 64;            // A buffer elems (16KB)
  constexpr int BBUF = BN * 64;             // B buffer elems (12/16/24KB)
  constexpr int CP = BN + 8;                // padded C-tile stride (elems)
  static_assert(128 * CP <= 2 * ABUF + 2 * BBUF, "C tile must fit in smem");
  __shared__ __align__(16) __hip_bfloat16 smem[2 * ABUF + 2 * BBUF];
  __hip_bfloat16* As = smem;
  __hip_bfloat16* Bs = smem + 2 * ABUF;
  const int m0 = blockIdx.x * 128;
  const int n0 = blockIdx.y * BN;
  const int tid  = threadIdx.x;
  const int lane = tid & 63;
  const int w    = tid >> 6;                // wave 0..3
  const int wr   = w >> 1;                  // 0..1 (M half, 64 rows)
  const int wc   = w & 1;                   // 0..1 (N half)
  const int lr   = lane & 15;
  const int kg   = lane >> 4;               // 0..3

  f32x4 acc[4][NF];
#pragma unroll
  for (int i = 0; i < 4; i++)
#pragma unroll
    for (int j = 0; j < NF; j++) acc[i][j] = (f32x4){0.f, 0.f, 0.f, 0.f};

  // staging: pass = 256 thr x 16B = 32 rows x 128B. Wave w rows w*8..w*8+7.
  // lane l: row w*8 + l/8, LDS slot l%8, global k-slot (l%8)^(l/8).
  const int prow = lane >> 3;               // 0..7
  const int pslot = lane & 7;
  const int gslot = pslot ^ prow;
  const __hip_bfloat16* aS = A  + (size_t)(m0 + w * 8 + prow) * K + gslot * 8;
  const __hip_bfloat16* bS = Bt + (size_t)(n0 + w * 8 + prow) * K + gslot * 8;
  const size_t K32g = (size_t)32 * K;       // 32-row pass stride (global)
  const int ldsw = w << 9;                  // w*512 elems (8 rows x 64)

  // per-wave loads per stage: 4 (A) + BPASS (B)
  auto stage = [&](int buf, int k0) {
    __hip_bfloat16* Ab = As + buf * ABUF + ldsw;
    __hip_bfloat16* Bb = Bs + buf * BBUF + ldsw;
#pragma unroll
    for (int p = 0; p < 4; p++)
      gl2lds16(Ab + p * 2048, aS + k0 + p * K32g);
#pragma unroll
    for (int p = 0; p < BPASS; p++)
      gl2lds16(Bb + p * 2048, bS + k0 + p * K32g);
  };

  // read-side swizzled slots (per-lane constants)
  const int rx = lr & 7;
  const int arow = wr * 64 + lr;            // + i*16
  const int brow = wc * (BN / 2) + lr;      // + j*16

  const int nt = K >> 6;                    // BK=64 tiles (12 or 48)
  stage(0, 0);
  stage(1, 64);

  for (int t = 0; t < nt; ++t) {
    const int cur = t & 1;
    // counted wait: tile t's own loads done (= 4+BPASS of t+1 in flight)
    if (t == nt - 1) {
      asm volatile("s_waitcnt vmcnt(0)" ::: "memory");
    } else {
      if constexpr (BN == 192)      asm volatile("s_waitcnt vmcnt(10)" ::: "memory");
      else if constexpr (BN == 128) asm volatile("s_waitcnt vmcnt(8)" ::: "memory");
      else                          asm volatile("s_waitcnt vmcnt(7)" ::: "memory");
    }
    asm volatile("s_barrier" ::: "memory");          // all waves: tile t ready

    const __hip_bfloat16* Ab = As + cur * ABUF;
    const __hip_bfloat16* Bb = Bs + cur * BBUF;
    bf16x8s af[2][4], bq[2][NF];
#pragma unroll
    for (int kk = 0; kk < 2; kk++) {
      const int sl = ((kk * 4 + kg) ^ rx) * 8;
#pragma unroll
      for (int i = 0; i < 4; i++)
        af[kk][i] = *reinterpret_cast<const bf16x8s*>(&Ab[(arow + i * 16) * 64 + sl]);
#pragma unroll
      for (int j = 0; j < NF; j++)
        bq[kk][j] = *reinterpret_cast<const bf16x8s*>(&Bb[(brow + j * 16) * 64 + sl]);
    }
    asm volatile("s_waitcnt lgkmcnt(0)" ::: "memory");  // frags in regs
    asm volatile("s_barrier" ::: "memory");             // all waves done reading

    if (t + 2 < nt) stage(cur, (t + 2) << 6);  // overwrite just-read buffer

#pragma unroll
    for (int kk = 0; kk < 2; kk++)
#pragma unroll
      for (int i = 0; i < 4; i++)
#pragma unroll
        for (int j = 0; j < NF; j++)
          acc[i][j] = __builtin_amdgcn_mfma_f32_16x16x32_bf16(
              af[kk][i], bq[kk][j], acc[i][j], 0, 0, 0);
  }

  // ---- epilogue: dump activated tile to LDS, then coalesced write-out ----
  __hip_bfloat16* Ct = smem;
#pragma unroll
  for (int i = 0; i < 4; i++)
#pragma unroll
    for (int j = 0; j < NF; j++) {
      int cl = wc * (BN / 2) + j * 16 + lr;      // col within tile
      float bv = bias[n0 + cl];
#pragma unroll
      for (int r = 0; r < 4; r++) {
        int rl = wr * 64 + i * 16 + kg * 4 + r;  // row within tile
        float v = acc[i][j][r] + bv;
        if (ACT == 1) v = 1.f / (1.f + __expf(-v));
        else if (ACT == 2) {
          float x = v;
          float z = 1.5957691216057308f * (x + 0.044715f * x * x * x);
          v = x / (1.f + __expf(-z));
        }
        if (RADD) v += __bfloat162float(R[(size_t)(m0 + rl) * N + n0 + cl]);
        Ct[rl * CP + cl] = __float2bfloat16(v);
      }
    }
  __syncthreads();

  // coalesced write-out: 16B chunks, 16 consecutive lanes = 256B runs
  constexpr int CPR = BN / 8;               // 16B chunks per row (12/16/24)
  constexpr int NPASS = 128 * CPR / 256;    // 6/8/12 passes
#pragma unroll
  for (int p = 0; p < NPASS; ++p) {
    int idx = p * 256 + tid;
    int row = idx / CPR;
    int ch  = idx - row * CPR;
    uint4 d = *reinterpret_cast<const uint4*>(&Ct[row * CP + ch * 8]);
    *reinterpret_cast<uint4*>(&Cb[(size_t)(m0 + row) * N + n0 + ch * 8]) = d;
  }
}

// ---------------------------------------------------------------------------
extern "C" void kernel_launch(void* const* d_in, const int* in_sizes, int n_in,
                              void* d_out, int out_size, void* d_ws, size_t ws_size,
                              hipStream_t stream)
{
  const int*   ids  = (const int*)d_in[0];
  const float* wemb = (const float*)d_in[1];
  const float* pemb = (const float*)d_in[2];
  const float* elns = (const float*)d_in[3];
  const float* elnb = (const float*)d_in[4];
  const float* retW = (const float*)d_in[5];
  const float* retb = (const float*)d_in[6];
  const float* ln1s = (const float*)d_in[7];
  const float* ln1b = (const float*)d_in[8];
  const float* W1   = (const float*)d_in[9];
  const float* b1   = (const float*)d_in[10];
  const float* W2   = (const float*)d_in[11];
  const float* b2   = (const float*)d_in[12];
  const float* ln2s = (const float*)d_in[13];
  const float* ln2b = (const float*)d_in[14];
  const float* fins = (const float*)d_in[15];
  const float* finb = (const float*)d_in[16];
  float* out = (float*)d_out;

  char* ws = (char*)d_ws;
  size_t off = 0;
  __hip_bfloat16* retWt = (__hip_bfloat16*)(ws + off); off += (size_t)NL * HD * HD * 2;
  __hip_bfloat16* W1t   = (__hip_bfloat16*)(ws + off); off += (size_t)NL * HD * ID * 2;
  __hip_bfloat16* W2t   = (__hip_bfloat16*)(ws + off); off += (size_t)NL * ID * HD * 2;
  __hip_bfloat16* hb    = (__hip_bfloat16*)(ws + off); off += (size_t)ROWS * HD * 2;  // residual h
  __hip_bfloat16* h1b   = (__hip_bfloat16*)(ws + off); off += (size_t)ROWS * HD * 2;  // h1
  __hip_bfloat16* yb    = (__hip_bfloat16*)(ws + off); off += (size_t)ROWS * HD * 2;  // h1+ffn2
  __hip_bfloat16* gb    = (__hip_bfloat16*)(ws + off); off += (size_t)ROWS * ID * 2;  // s / gelu out
  __hip_bfloat16* sb = gb;   // sigmoid out aliases gb (consumed before FFN1 rewrites)

  // merged prologue: 20736 transpose tiles + 2048 embed row-groups
  prologue_kernel<<<dim3(20736 + ROWS/4), 256, 0, stream>>>(
      retW, W1, W2, retWt, W1t, W2t, ids, wemb, pemb, elns, elnb, hb);

  for (int l = 0; l < NL; l++) {
    // s = sigmoid(h @ retW + rb) -> sb (bf16). BN=96 (512 blocks = 2/CU)
    gemm_mfma_kernel<96, 1, 0><<<dim3(ROWS/128, HD/96), 256, 0, stream>>>(
        hb, retWt + (size_t)l * HD * HD, retb + (size_t)l * HD,
        nullptr, sb, ROWS, HD, HD);
    // h1 = LN(h + retention(s))  [fused scan+LN, warm-up 16]
    scan_ln_kernel<<<NB * (SL/32), 768, 0, stream>>>(sb, hb,
        ln1s + (size_t)l * HD, ln1b + (size_t)l * HD, h1b);
    // g = gelu(h1 @ W1 + b1) -> gb (bf16). BN=192 (1024 blocks = 4/CU)
    gemm_mfma_kernel<192, 2, 0><<<dim3(ROWS/128, ID/192), 256, 0, stream>>>(
        h1b, W1t + (size_t)l * ID * HD, b1 + (size_t)l * ID,
        nullptr, gb, ROWS, ID, HD);
    // y = h1 + (g @ W2 + b2) -> yb (bf16). BN=96 (512 blocks = 2/CU)
    gemm_mfma_kernel<96, 0, 1><<<dim3(ROWS/128, HD/96), 256, 0, stream>>>(
        gb, W2t + (size_t)l * HD * ID, b2 + (size_t)l * HD,
        h1b, yb, ROWS, HD, ID);
    if (l < NL - 1) {
      // h = LN(y)
      ln_row_kernel<0><<<ROWS/4, 256, 0, stream>>>(yb,
          ln2s + (size_t)l * HD, ln2b + (size_t)l * HD, hb, nullptr);
    } else {
      // last layer: out = LNf(bf16(LN2(y))) fused — skips hb round-trip
      ln2_final_kernel<<<ROWS/4, 256, 0, stream>>>(yb,
          ln2s + (size_t)l * HD, ln2b + (size_t)l * HD, fins, finb, out);
    }
  }
}